// Round 10
// baseline (349.491 us; speedup 1.0000x reference)
//
#include <hip/hip_runtime.h>
#include <math.h>

#define B_   32
#define NCq  62
#define F_   256
#define NE   512
#define M_   (B_*NCq)      // 1984
#define NCOL (NCq*F_)      // 15872
#define NZ   (M_*NCq)      // 123008
#define EPSF 1e-6f

typedef unsigned short ushort_t;
typedef unsigned int uint_t;
typedef _Float16 h8_t __attribute__((ext_vector_type(8)));
typedef float f4_t __attribute__((ext_vector_type(4)));

__device__ __forceinline__ float eluf(float x){ return x > 0.0f ? x : expm1f(x); }

// XOR-swizzled LDS offset, BK=32: row stride 32 f16 (64B), 4 pieces of 8 f16 (16B)
// verified 0 bank conflicts (R6 counters)
__device__ __forceinline__ int sw_off(int row, int piece){
    return row*32 + ((piece ^ ((row>>1)&3))*8);
}
// async global->LDS, 16B per lane; lds base wave-uniform, lane i lands at base+i*16
__device__ __forceinline__ void gl_lds(const _Float16* g, _Float16* l){
    __builtin_amdgcn_global_load_lds((const __attribute__((address_space(1))) void*)g,
                                     (__attribute__((address_space(3))) void*)l, 16, 0, 0);
}

// ---------------- theta, transposed + f16: THf[n][k] = f16(TH[k][n]) ----------------
__global__ __launch_bounds__(256) void k_split_th(const float* __restrict__ TH,
                                                  _Float16* __restrict__ THf){
    __shared__ float tile[32][33];
    int n0 = blockIdx.x * 32, k0 = blockIdx.y * 32;
    int tid = threadIdx.x;
    int cc = tid & 31, rr = tid >> 5;
    #pragma unroll
    for(int p=0;p<4;p++){
        int kk = rr + p*8;
        tile[kk][cc] = TH[(size_t)(k0+kk)*NCOL + n0 + cc];
    }
    __syncthreads();
    #pragma unroll
    for(int p=0;p<4;p++){
        int nn = rr + p*8;
        THf[(size_t)(n0+nn)*F_ + k0 + cc] = (_Float16)tile[cc][nn];
    }
}

// ---------------- codebook: f16 copy, norms (fp32), output copy ----------------
__global__ __launch_bounds__(256) void k_prep(const float* __restrict__ cb,
                                              _Float16* __restrict__ CBf,
                                              float* __restrict__ cnorm, float* __restrict__ out_cb){
    int e = blockIdx.x; int d = threadIdx.x;
    float v = cb[e*F_ + d];
    out_cb[e*F_ + d] = v;
    CBf[e*F_ + d] = (_Float16)v;
    float s = v*v;
    #pragma unroll
    for(int m=32;m;m>>=1) s += __shfl_xor(s, m, 64);
    __shared__ float red[4];
    if((threadIdx.x & 63)==0) red[threadIdx.x>>6] = s;
    __syncthreads();
    if(threadIdx.x==0) cnorm[e] = red[0]+red[1]+red[2]+red[3];
}

// ---------------- o = p@x+bias; t = o@q; write f16 t ----------------
__global__ __launch_bounds__(256) void k_ot(const float* __restrict__ x, const float* __restrict__ p,
                                            const float* __restrict__ bias, const float* __restrict__ q,
                                            _Float16* __restrict__ Tf){
    int bi = blockIdx.x; int d = threadIdx.x;
    int b = bi / NCq, i = bi % NCq;
    __shared__ float pr[NCq];
    __shared__ float orow[F_];
    if(d < NCq) pr[d] = p[i*NCq + d];
    __syncthreads();
    float acc = bias[i*F_ + d];
    const float* xb = x + (size_t)b*NCq*F_ + d;
    #pragma unroll 2
    for(int j=0;j<NCq;j++) acc = fmaf(pr[j], xb[j*F_], acc);
    orow[d] = acc;
    __syncthreads();
    float t = 0.f;
    #pragma unroll 4
    for(int k=0;k<F_;k++) t = fmaf(orow[k], q[k*F_ + d], t);
    Tf[bi*F_ + d] = (_Float16)t;
}

// ---------------- G = ELU(T @ theta), f16 in/out; BK=32, double-buffered LDS ----------------
// block 128m x 256n; 4 waves 2x2, wave tile 64x128; one barrier per K-chunk
__global__ __launch_bounds__(256,3) void k_gemm_g(const _Float16* __restrict__ Tf,
                                                  const _Float16* __restrict__ THf,
                                                  _Float16* __restrict__ Gf){
    __shared__ _Float16 As[2][128*32], Bs[2][256*32];  // 2 x (8+16) = 48 KB
    int tid = threadIdx.x;
    int l = tid & 63, w = tid >> 6;
    int wr = w >> 1, wc = w & 1;
    int m = l & 15, quad = l >> 4;
    int row0 = blockIdx.x * 128, col0 = blockIdx.y * 256;
    int wbase = tid & 192;   // w*64
    f4_t acc[4][8] = {};
    auto stage = [&](int kc, int buf){
        #pragma unroll
        for(int p2=0;p2<2;p2++){
            int idx = p2*256 + tid;
            int row = idx >> 2, psw = idx & 3;
            int porig = psw ^ ((row>>1)&3);
            int rclamp = row0 + row; if(rclamp >= M_) rclamp = M_-1;
            gl_lds(&Tf[(size_t)rclamp*F_ + kc + porig*8], &As[buf][(p2*256 + wbase)*8]);
        }
        #pragma unroll
        for(int p2=0;p2<4;p2++){
            int idx = p2*256 + tid;
            int row = idx >> 2, psw = idx & 3;
            int porig = psw ^ ((row>>1)&3);
            gl_lds(&THf[(size_t)(col0 + row)*F_ + kc + porig*8], &Bs[buf][(p2*256 + wbase)*8]);
        }
    };
    stage(0, 0);
    #pragma unroll
    for(int i=0;i<8;i++){
        __syncthreads();                       // drains loads issued one chunk ago
        if(i < 7) stage((i+1)*32, (i+1)&1);    // prefetch next chunk into other buffer
        const _Float16* Ab = As[i&1];
        const _Float16* Bb = Bs[i&1];
        h8_t a[4];
        #pragma unroll
        for(int mt=0;mt<4;mt++){
            int row = wr*64 + mt*16 + m;
            a[mt] = *(const h8_t*)&Ab[sw_off(row, quad)];
        }
        #pragma unroll
        for(int nt=0;nt<8;nt++){
            int col = wc*128 + nt*16 + m;
            h8_t b = *(const h8_t*)&Bb[sw_off(col, quad)];
            #pragma unroll
            for(int mt=0;mt<4;mt++)
                acc[mt][nt] = __builtin_amdgcn_mfma_f32_16x16x32_f16(a[mt], b, acc[mt][nt], 0,0,0);
        }
    }
    #pragma unroll
    for(int mt=0;mt<4;mt++){
        #pragma unroll
        for(int nt=0;nt<8;nt++){
            int rowb = row0 + wr*64 + mt*16 + quad*4;
            int colb = col0 + wc*128 + nt*16 + m;
            #pragma unroll
            for(int r=0;r<4;r++){
                int row = rowb + r;
                if(row < M_) Gf[(size_t)row*NCOL + colb] = (_Float16)eluf(acc[mt][nt][r]);
            }
        }
    }
}

// ---------------- den + loss; renormalize Gf IN PLACE to f16 z (vectorized) ----------------
__global__ __launch_bounds__(256) void k_den(_Float16* __restrict__ Gf, double* __restrict__ loss_sum){
    int bi = blockIdx.x;
    int tid = threadIdx.x;
    int dg = tid & 31, jg = tid >> 5;
    __shared__ float l1[8][32][8];
    __shared__ float l2[8][32][8];
    __shared__ float invsh[32][8];
    float v[8][8];
    float a1[8] = {}, a2[8] = {};
    size_t base = (size_t)bi*NCOL + dg*8;
    #pragma unroll
    for(int p=0;p<8;p++){
        int j = jg + p*8;
        if(j < NCq){
            h8_t g = *(const h8_t*)&Gf[base + (size_t)j*F_];
            #pragma unroll
            for(int i=0;i<8;i++){
                float t = (float)g[i];
                v[p][i] = t;
                a1[i] += fabsf(t);
                a2[i] = fmaf(t, t, a2[i]);
            }
        }
    }
    #pragma unroll
    for(int i=0;i<8;i++){ l1[jg][dg][i] = a1[i]; l2[jg][dg][i] = a2[i]; }
    __syncthreads();
    if(jg == 0){
        float part = 0.f;
        #pragma unroll
        for(int i=0;i<8;i++){
            float s1 = 0.f, s2 = 0.f;
            #pragma unroll
            for(int q2=0;q2<8;q2++){ s1 += l1[q2][dg][i]; s2 += l2[q2][dg][i]; }
            float inv = 1.0f/(s1 + EPSF);
            invsh[dg][i] = inv;
            part += s2*inv*inv;
        }
        #pragma unroll
        for(int mk=16;mk;mk>>=1) part += __shfl_xor(part, mk, 32);
        if(tid == 0) atomicAdd(loss_sum, (double)part);
    }
    __syncthreads();
    float inv[8];
    #pragma unroll
    for(int i=0;i<8;i++) inv[i] = invsh[dg][i];
    #pragma unroll
    for(int p=0;p<8;p++){
        int j = jg + p*8;
        if(j < NCq){
            h8_t z;
            #pragma unroll
            for(int i=0;i<8;i++) z[i] = (_Float16)(v[p][i]*inv[i]);
            *(h8_t*)&Gf[base + (size_t)j*F_] = z;
        }
    }
}

// ---------------- VQ: dist GEMM (f16 MFMA); BK=32 double-buffered; argmin ----------------
// block 128 rows x 256 codes; 4 waves 2x2, wave tile 64x128
__global__ __launch_bounds__(256,3) void k_vq(const _Float16* __restrict__ Zf,
                                              const _Float16* __restrict__ CBf,
                                              const float* __restrict__ cnorm,
                                              float* __restrict__ pmin, int* __restrict__ pidx){
    __shared__ _Float16 As[2][128*32], Bs[2][256*32];   // 48 KB
    int tid = threadIdx.x;
    int l = tid & 63, w = tid >> 6;
    int wr = w >> 1, wc = w & 1;
    int m = l & 15, quad = l >> 4;
    int n_base = blockIdx.x * 128;
    int e0 = blockIdx.y * 256;
    int wbase = tid & 192;
    f4_t acc[4][8] = {};
    auto stage = [&](int kc, int buf){
        #pragma unroll
        for(int p2=0;p2<2;p2++){
            int idx = p2*256 + tid;
            int row = idx >> 2, psw = idx & 3;
            int porig = psw ^ ((row>>1)&3);
            gl_lds(&Zf[(size_t)(n_base + row)*F_ + kc + porig*8], &As[buf][(p2*256 + wbase)*8]);
        }
        #pragma unroll
        for(int p2=0;p2<4;p2++){
            int idx = p2*256 + tid;
            int row = idx >> 2, psw = idx & 3;
            int porig = psw ^ ((row>>1)&3);
            gl_lds(&CBf[(size_t)(e0 + row)*F_ + kc + porig*8], &Bs[buf][(p2*256 + wbase)*8]);
        }
    };
    stage(0, 0);
    #pragma unroll
    for(int i=0;i<8;i++){
        __syncthreads();
        if(i < 7) stage((i+1)*32, (i+1)&1);
        const _Float16* Ab = As[i&1];
        const _Float16* Bb = Bs[i&1];
        h8_t a[4];
        #pragma unroll
        for(int mt=0;mt<4;mt++){
            int row = wr*64 + mt*16 + m;
            a[mt] = *(const h8_t*)&Ab[sw_off(row, quad)];
        }
        #pragma unroll
        for(int nt=0;nt<8;nt++){
            int col = wc*128 + nt*16 + m;
            h8_t b = *(const h8_t*)&Bb[sw_off(col, quad)];
            #pragma unroll
            for(int mt=0;mt<4;mt++)
                acc[mt][nt] = __builtin_amdgcn_mfma_f32_16x16x32_f16(a[mt], b, acc[mt][nt], 0,0,0);
        }
    }
    // epilogue: score = cnorm - 2*dot; argmin over the 128 codes this wave owns
    #pragma unroll
    for(int mt=0;mt<4;mt++){
        float bv[4]; int bix[4];
        #pragma unroll
        for(int r=0;r<4;r++){ bv[r] = 3.4e38f; bix[r] = 0; }
        #pragma unroll
        for(int nt=0;nt<8;nt++){
            int e = e0 + wc*128 + nt*16 + m;
            float cn = cnorm[e];
            #pragma unroll
            for(int r=0;r<4;r++){
                float vv = cn - 2.0f*acc[mt][nt][r];
                if(vv < bv[r]){ bv[r] = vv; bix[r] = e; }
            }
        }
        #pragma unroll
        for(int r=0;r<4;r++){
            float vv = bv[r]; int ix = bix[r];
            #pragma unroll
            for(int mk=8;mk;mk>>=1){
                float ov = __shfl_xor(vv, mk, 64);
                int   oi = __shfl_xor(ix, mk, 64);
                if(ov < vv || (ov == vv && oi < ix)){ vv = ov; ix = oi; }
            }
            if(m == 0){
                int n = n_base + wr*64 + mt*16 + quad*4 + r;
                int slot = blockIdx.y*2 + wc;
                pmin[n*4 + slot] = vv;
                pidx[n*4 + slot] = ix;
            }
        }
    }
}

// ---------------- finalize: one block per batch b; LDS histogram ----------------
__global__ __launch_bounds__(1024) void k_fin(const float* __restrict__ pmin, const int* __restrict__ pidx,
                                              int* __restrict__ idx,
                                              int* __restrict__ counts, int* __restrict__ countb,
                                              double* __restrict__ loss_sum){
    int b = blockIdx.x;
    int t = threadIdx.x;
    __shared__ int hist[NE];
    __shared__ float red[16];
    #pragma unroll
    for(int e=t; e<NE; e+=1024) hist[e] = 0;
    __syncthreads();
    float msum = 0.f;
    int n0 = b * (NCq*NCq);
    for(int i=t; i<NCq*NCq; i+=1024){
        int n = n0 + i;
        float4 pv = *(const float4*)&pmin[n*4];
        int4   pi = *(const int4*)&pidx[n*4];
        float bv = pv.x; int bix = pi.x;
        if(pv.y < bv || (pv.y==bv && pi.y<bix)){ bv=pv.y; bix=pi.y; }
        if(pv.z < bv || (pv.z==bv && pi.z<bix)){ bv=pv.z; bix=pi.z; }
        if(pv.w < bv || (pv.w==bv && pi.w<bix)){ bv=pv.w; bix=pi.w; }
        idx[n] = bix;
        atomicAdd(&hist[bix], 1);
        msum += bv;
    }
    #pragma unroll
    for(int m=32;m;m>>=1) msum += __shfl_xor(msum, m, 64);
    if((t&63)==0) red[t>>6] = msum;
    __syncthreads();
    if(t==0){
        float s = 0.f;
        #pragma unroll
        for(int i2=0;i2<16;i2++) s += red[i2];
        atomicAdd(loss_sum, (double)s);
    }
    for(int e=t; e<NE; e+=1024){
        int c = hist[e];
        countb[b*NE + e] = c;
        if(c) atomicAdd(&counts[e], c);
    }
}

// ---------------- scalars: vq_loss and usage ----------------
__global__ __launch_bounds__(256) void k_scal(const int* __restrict__ counts, const double* __restrict__ loss_sum,
                                              float* __restrict__ out){
    int t = threadIdx.x;
    float ent = 0.f;
    for(int e=t; e<NE; e+=256){
        float pr = (float)counts[e] / (float)NZ;
        ent += pr * logf(pr + 1e-10f);
    }
    #pragma unroll
    for(int m=32;m;m>>=1) ent += __shfl_xor(ent,m,64);
    __shared__ float red[4];
    if((t&63)==0) red[t>>6]=ent;
    __syncthreads();
    if(t==0){
        float e2 = red[0]+red[1]+red[2]+red[3];
        out[1+NZ] = expf(-e2);
        out[0] = (float)(1.25 * (*loss_sum) / ((double)NZ * (double)F_));
    }
}

// ---------------- SE block ----------------
__global__ __launch_bounds__(256) void k_se(const int* __restrict__ countb, const float* __restrict__ cb,
                                            const float* __restrict__ w1, const float* __restrict__ b1,
                                            const float* __restrict__ w2, const float* __restrict__ b2,
                                            float* __restrict__ s2p1){
    int b = blockIdx.x; int d = threadIdx.x;
    __shared__ float cnt[NE];
    __shared__ float s_sh[F_];
    __shared__ float h_sh[16];
    cnt[d]       = (float)countb[b*NE + d];
    cnt[d + 256] = (float)countb[b*NE + d + 256];
    __syncthreads();
    float s = 0.f;
    for(int e=0;e<NE;e++) s = fmaf(cnt[e], cb[e*F_ + d], s);
    s *= (1.0f/(float)(NCq*NCq));
    s_sh[d] = s;
    __syncthreads();
    if(d < 16){
        float h = b1[d];
        for(int k=0;k<F_;k++) h = fmaf(s_sh[k], w1[k*16 + d], h);
        h_sh[d] = fmaxf(h, 0.f);
    }
    __syncthreads();
    float v = b2[d];
    #pragma unroll
    for(int r=0;r<16;r++) v = fmaf(h_sh[r], w2[r*F_ + d], v);
    s2p1[b*F_ + d] = 1.0f + 1.0f/(1.0f + expf(-v));
}

// ---------------- w[b,e] = sum_d elu(c[e,d]*(1+s2[b,d])) ----------------
__global__ __launch_bounds__(256) void k_w(const float* __restrict__ cb, const float* __restrict__ s2p1,
                                           float* __restrict__ wtab){
    int b = blockIdx.x; int eg = blockIdx.y;
    int wv = threadIdx.x>>6, lane = threadIdx.x&63;
    __shared__ float m_sh[F_];
    m_sh[threadIdx.x] = s2p1[b*F_ + threadIdx.x];
    __syncthreads();
    int e = eg*4 + wv;
    float4 c4 = *(const float4*)&cb[e*F_ + lane*4];
    float s = eluf(c4.x*m_sh[lane*4]) + eluf(c4.y*m_sh[lane*4+1])
            + eluf(c4.z*m_sh[lane*4+2]) + eluf(c4.w*m_sh[lane*4+3]);
    #pragma unroll
    for(int m2=32;m2;m2>>=1) s += __shfl_xor(s,m2,64);
    if(lane==0) wtab[b*NE + e] = s;
}

// ---------------- final: out[b,i,j] = normalize_j(elu(w[b, idx])) ----------------
__global__ __launch_bounds__(64) void k_out(const int* __restrict__ idx, const float* __restrict__ wtab,
                                            float* __restrict__ out){
    int bi = blockIdx.x; int j = threadIdx.x;
    int b = bi / NCq;
    float v = 0.f;
    if(j < NCq) v = eluf(wtab[b*NE + idx[bi*NCq + j]]);
    float a = fabsf(v);
    #pragma unroll
    for(int m=32;m;m>>=1) a += __shfl_xor(a,m,64);
    if(j < NCq) out[1 + bi*NCq + j] = v / (a + EPSF);
}

extern "C" void kernel_launch(void* const* d_in, const int* in_sizes, int n_in,
                              void* d_out, int out_size, void* d_ws, size_t ws_size,
                              hipStream_t stream){
    (void)in_sizes; (void)n_in; (void)out_size; (void)ws_size;
    const float* x    = (const float*)d_in[0];
    const float* p    = (const float*)d_in[1];
    const float* bias = (const float*)d_in[2];
    const float* q    = (const float*)d_in[3];
    const float* th   = (const float*)d_in[4];
    const float* cb   = (const float*)d_in[5];
    const float* w1   = (const float*)d_in[6];
    const float* b1   = (const float*)d_in[7];
    const float* w2   = (const float*)d_in[8];
    const float* b2   = (const float*)d_in[9];
    float* out = (float*)d_out;
    char* ws = (char*)d_ws;
    size_t off = 0;
    auto alloc = [&](size_t bytes){ void* ptr = ws + off; off = (off + bytes + 255) & ~255ull; return ptr; };
    _Float16* Gf   = (_Float16*)alloc((size_t)NZ*F_*sizeof(_Float16));      // 60 MiB (doubles as Zf)
    _Float16* THf  = (_Float16*)alloc((size_t)F_*NCOL*sizeof(_Float16));    // 7.75 MiB ([n][k])
    _Float16* Tf   = (_Float16*)alloc((size_t)M_*F_*sizeof(_Float16));
    _Float16* CBf  = (_Float16*)alloc((size_t)NE*F_*sizeof(_Float16));
    float*    CN   = (float*)   alloc((size_t)NE*sizeof(float));
    float*    PMIN = (float*)   alloc((size_t)NZ*4*sizeof(float));
    int*      PIDX = (int*)     alloc((size_t)NZ*4*sizeof(int));
    int*      IDX  = (int*)     alloc((size_t)NZ*sizeof(int));
    char*     zbase= (char*)    alloc(8 + NE*sizeof(int));
    double*   LOSS   = (double*)zbase;
    int*      COUNTS = (int*)(zbase + 8);
    int*      COUNTB = (int*)   alloc((size_t)B_*NE*sizeof(int));
    float*    S2P1 = (float*)alloc((size_t)B_*F_*sizeof(float));
    float*    WTAB = (float*)alloc((size_t)B_*NE*sizeof(float));

    (void)hipMemsetAsync(zbase, 0, 8 + NE*sizeof(int), stream);
    dim3 gth(NCOL/32, F_/32);
    k_split_th<<<gth, 256, 0, stream>>>(th, THf);
    k_prep<<<NE, 256, 0, stream>>>(cb, CBf, CN, out + 1 + NZ + 1);
    k_ot<<<M_, 256, 0, stream>>>(x, p, bias, q, Tf);
    dim3 g3((M_ + 127)/128, NCOL/256);   // 16 x 62 (tail rows guarded)
    k_gemm_g<<<g3, 256, 0, stream>>>(Tf, THf, Gf);
    k_den<<<M_, 256, 0, stream>>>(Gf, LOSS);
    dim3 g5(NZ/128, 2);
    k_vq<<<g5, 256, 0, stream>>>(Gf, CBf, CN, PMIN, PIDX);
    k_fin<<<B_, 1024, 0, stream>>>(PMIN, PIDX, IDX, COUNTS, COUNTB, LOSS);
    k_scal<<<1, 256, 0, stream>>>(COUNTS, LOSS, out);
    k_se<<<B_, 256, 0, stream>>>(COUNTB, cb, w1, b1, w2, b2, S2P1);
    dim3 g8(B_, NE/4);
    k_w<<<g8, 256, 0, stream>>>(cb, S2P1, WTAB);
    k_out<<<M_, 64, 0, stream>>>(IDX, WTAB, out);
}

// Round 11
// 302.061 us; speedup vs baseline: 1.1570x; 1.1570x over previous
//
#include <hip/hip_runtime.h>
#include <math.h>

#define B_   32
#define NCq  62
#define F_   256
#define NE   512
#define M_   (B_*NCq)      // 1984
#define NCOL (NCq*F_)      // 15872
#define NZ   (M_*NCq)      // 123008
#define EPSF 1e-6f

typedef unsigned short ushort_t;
typedef unsigned int uint_t;
typedef _Float16 h8_t __attribute__((ext_vector_type(8)));
typedef float f4_t __attribute__((ext_vector_type(4)));

__device__ __forceinline__ float eluf(float x){ return x > 0.0f ? x : expm1f(x); }

// XOR-swizzled LDS offset, BK=32: row stride 32 f16 (64B), 4 pieces of 8 f16 (16B)
// verified 0 bank conflicts (R6 counters)
__device__ __forceinline__ int sw_off(int row, int piece){
    return row*32 + ((piece ^ ((row>>1)&3))*8);
}
// async global->LDS, 16B per lane; lds base wave-uniform, lane i lands at base+i*16
__device__ __forceinline__ void gl_lds(const _Float16* g, _Float16* l){
    __builtin_amdgcn_global_load_lds((const __attribute__((address_space(1))) void*)g,
                                     (__attribute__((address_space(3))) void*)l, 16, 0, 0);
}

// ---------------- theta, transposed + f16: THf[n][k] = f16(TH[k][n]) ----------------
__global__ __launch_bounds__(256) void k_split_th(const float* __restrict__ TH,
                                                  _Float16* __restrict__ THf){
    __shared__ float tile[32][33];
    int n0 = blockIdx.x * 32, k0 = blockIdx.y * 32;
    int tid = threadIdx.x;
    int cc = tid & 31, rr = tid >> 5;
    #pragma unroll
    for(int p=0;p<4;p++){
        int kk = rr + p*8;
        tile[kk][cc] = TH[(size_t)(k0+kk)*NCOL + n0 + cc];
    }
    __syncthreads();
    #pragma unroll
    for(int p=0;p<4;p++){
        int nn = rr + p*8;
        THf[(size_t)(n0+nn)*F_ + k0 + cc] = (_Float16)tile[cc][nn];
    }
}

// ---------------- codebook: f16 copy, norms (fp32), output copy ----------------
__global__ __launch_bounds__(256) void k_prep(const float* __restrict__ cb,
                                              _Float16* __restrict__ CBf,
                                              float* __restrict__ cnorm, float* __restrict__ out_cb){
    int e = blockIdx.x; int d = threadIdx.x;
    float v = cb[e*F_ + d];
    out_cb[e*F_ + d] = v;
    CBf[e*F_ + d] = (_Float16)v;
    float s = v*v;
    #pragma unroll
    for(int m=32;m;m>>=1) s += __shfl_xor(s, m, 64);
    __shared__ float red[4];
    if((threadIdx.x & 63)==0) red[threadIdx.x>>6] = s;
    __syncthreads();
    if(threadIdx.x==0) cnorm[e] = red[0]+red[1]+red[2]+red[3];
}

// ---------------- o = p@x+bias; t = o@q; write f16 t ----------------
__global__ __launch_bounds__(256) void k_ot(const float* __restrict__ x, const float* __restrict__ p,
                                            const float* __restrict__ bias, const float* __restrict__ q,
                                            _Float16* __restrict__ Tf){
    int bi = blockIdx.x; int d = threadIdx.x;
    int b = bi / NCq, i = bi % NCq;
    __shared__ float pr[NCq];
    __shared__ float orow[F_];
    if(d < NCq) pr[d] = p[i*NCq + d];
    __syncthreads();
    float acc = bias[i*F_ + d];
    const float* xb = x + (size_t)b*NCq*F_ + d;
    #pragma unroll 2
    for(int j=0;j<NCq;j++) acc = fmaf(pr[j], xb[j*F_], acc);
    orow[d] = acc;
    __syncthreads();
    float t = 0.f;
    #pragma unroll 4
    for(int k=0;k<F_;k++) t = fmaf(orow[k], q[k*F_ + d], t);
    Tf[bi*F_ + d] = (_Float16)t;
}

// ---------------- G = ELU(T @ theta), f16 in/out; BK=32, double-buffered LDS ----------------
// block 128m x 256n; 4 waves 2x2, wave tile 64x128; one barrier per K-chunk
__global__ __launch_bounds__(256,2) void k_gemm_g(const _Float16* __restrict__ Tf,
                                                  const _Float16* __restrict__ THf,
                                                  _Float16* __restrict__ Gf){
    __shared__ _Float16 As[2][128*32], Bs[2][256*32];  // 2 x (8+16) = 48 KB
    int tid = threadIdx.x;
    int l = tid & 63, w = tid >> 6;
    int wr = w >> 1, wc = w & 1;
    int m = l & 15, quad = l >> 4;
    int row0 = blockIdx.x * 128, col0 = blockIdx.y * 256;
    int wbase = tid & 192;   // w*64
    f4_t acc[4][8] = {};
    auto stage = [&](int kc, int buf){
        #pragma unroll
        for(int p2=0;p2<2;p2++){
            int idx = p2*256 + tid;
            int row = idx >> 2, psw = idx & 3;
            int porig = psw ^ ((row>>1)&3);
            int rclamp = row0 + row; if(rclamp >= M_) rclamp = M_-1;
            gl_lds(&Tf[(size_t)rclamp*F_ + kc + porig*8], &As[buf][(p2*256 + wbase)*8]);
        }
        #pragma unroll
        for(int p2=0;p2<4;p2++){
            int idx = p2*256 + tid;
            int row = idx >> 2, psw = idx & 3;
            int porig = psw ^ ((row>>1)&3);
            gl_lds(&THf[(size_t)(col0 + row)*F_ + kc + porig*8], &Bs[buf][(p2*256 + wbase)*8]);
        }
    };
    stage(0, 0);
    #pragma unroll
    for(int i=0;i<8;i++){
        __syncthreads();                       // drains loads issued one chunk ago
        if(i < 7) stage((i+1)*32, (i+1)&1);    // prefetch next chunk into other buffer
        const _Float16* Ab = As[i&1];
        const _Float16* Bb = Bs[i&1];
        h8_t a[4];
        #pragma unroll
        for(int mt=0;mt<4;mt++){
            int row = wr*64 + mt*16 + m;
            a[mt] = *(const h8_t*)&Ab[sw_off(row, quad)];
        }
        #pragma unroll
        for(int nt=0;nt<8;nt++){
            int col = wc*128 + nt*16 + m;
            h8_t b = *(const h8_t*)&Bb[sw_off(col, quad)];
            #pragma unroll
            for(int mt=0;mt<4;mt++)
                acc[mt][nt] = __builtin_amdgcn_mfma_f32_16x16x32_f16(a[mt], b, acc[mt][nt], 0,0,0);
        }
    }
    #pragma unroll
    for(int mt=0;mt<4;mt++){
        #pragma unroll
        for(int nt=0;nt<8;nt++){
            int rowb = row0 + wr*64 + mt*16 + quad*4;
            int colb = col0 + wc*128 + nt*16 + m;
            #pragma unroll
            for(int r=0;r<4;r++){
                int row = rowb + r;
                if(row < M_) Gf[(size_t)row*NCOL + colb] = (_Float16)eluf(acc[mt][nt][r]);
            }
        }
    }
}

// ---------------- den + loss; renormalize Gf IN PLACE to f16 z (vectorized) ----------------
__global__ __launch_bounds__(256) void k_den(_Float16* __restrict__ Gf, double* __restrict__ loss_sum){
    int bi = blockIdx.x;
    int tid = threadIdx.x;
    int dg = tid & 31, jg = tid >> 5;
    __shared__ float l1[8][32][8];
    __shared__ float l2[8][32][8];
    __shared__ float invsh[32][8];
    float v[8][8];
    float a1[8] = {}, a2[8] = {};
    size_t base = (size_t)bi*NCOL + dg*8;
    #pragma unroll
    for(int p=0;p<8;p++){
        int j = jg + p*8;
        if(j < NCq){
            h8_t g = *(const h8_t*)&Gf[base + (size_t)j*F_];
            #pragma unroll
            for(int i=0;i<8;i++){
                float t = (float)g[i];
                v[p][i] = t;
                a1[i] += fabsf(t);
                a2[i] = fmaf(t, t, a2[i]);
            }
        }
    }
    #pragma unroll
    for(int i=0;i<8;i++){ l1[jg][dg][i] = a1[i]; l2[jg][dg][i] = a2[i]; }
    __syncthreads();
    if(jg == 0){
        float part = 0.f;
        #pragma unroll
        for(int i=0;i<8;i++){
            float s1 = 0.f, s2 = 0.f;
            #pragma unroll
            for(int q2=0;q2<8;q2++){ s1 += l1[q2][dg][i]; s2 += l2[q2][dg][i]; }
            float inv = 1.0f/(s1 + EPSF);
            invsh[dg][i] = inv;
            part += s2*inv*inv;
        }
        #pragma unroll
        for(int mk=16;mk;mk>>=1) part += __shfl_xor(part, mk, 32);
        if(tid == 0) atomicAdd(loss_sum, (double)part);
    }
    __syncthreads();
    float inv[8];
    #pragma unroll
    for(int i=0;i<8;i++) inv[i] = invsh[dg][i];
    #pragma unroll
    for(int p=0;p<8;p++){
        int j = jg + p*8;
        if(j < NCq){
            h8_t z;
            #pragma unroll
            for(int i=0;i<8;i++) z[i] = (_Float16)(v[p][i]*inv[i]);
            *(h8_t*)&Gf[base + (size_t)j*F_] = z;
        }
    }
}

// ---------------- VQ: dist GEMM (f16 MFMA); BK=32 double-buffered; argmin ----------------
// block 128 rows x 256 codes; 4 waves 2x2, wave tile 64x128
__global__ __launch_bounds__(256,2) void k_vq(const _Float16* __restrict__ Zf,
                                              const _Float16* __restrict__ CBf,
                                              const float* __restrict__ cnorm,
                                              float* __restrict__ pmin, int* __restrict__ pidx){
    __shared__ _Float16 As[2][128*32], Bs[2][256*32];   // 48 KB
    int tid = threadIdx.x;
    int l = tid & 63, w = tid >> 6;
    int wr = w >> 1, wc = w & 1;
    int m = l & 15, quad = l >> 4;
    int n_base = blockIdx.x * 128;
    int e0 = blockIdx.y * 256;
    int wbase = tid & 192;
    f4_t acc[4][8] = {};
    auto stage = [&](int kc, int buf){
        #pragma unroll
        for(int p2=0;p2<2;p2++){
            int idx = p2*256 + tid;
            int row = idx >> 2, psw = idx & 3;
            int porig = psw ^ ((row>>1)&3);
            gl_lds(&Zf[(size_t)(n_base + row)*F_ + kc + porig*8], &As[buf][(p2*256 + wbase)*8]);
        }
        #pragma unroll
        for(int p2=0;p2<4;p2++){
            int idx = p2*256 + tid;
            int row = idx >> 2, psw = idx & 3;
            int porig = psw ^ ((row>>1)&3);
            gl_lds(&CBf[(size_t)(e0 + row)*F_ + kc + porig*8], &Bs[buf][(p2*256 + wbase)*8]);
        }
    };
    stage(0, 0);
    #pragma unroll
    for(int i=0;i<8;i++){
        __syncthreads();
        if(i < 7) stage((i+1)*32, (i+1)&1);
        const _Float16* Ab = As[i&1];
        const _Float16* Bb = Bs[i&1];
        h8_t a[4];
        #pragma unroll
        for(int mt=0;mt<4;mt++){
            int row = wr*64 + mt*16 + m;
            a[mt] = *(const h8_t*)&Ab[sw_off(row, quad)];
        }
        #pragma unroll
        for(int nt=0;nt<8;nt++){
            int col = wc*128 + nt*16 + m;
            h8_t b = *(const h8_t*)&Bb[sw_off(col, quad)];
            #pragma unroll
            for(int mt=0;mt<4;mt++)
                acc[mt][nt] = __builtin_amdgcn_mfma_f32_16x16x32_f16(a[mt], b, acc[mt][nt], 0,0,0);
        }
    }
    // epilogue: score = cnorm - 2*dot; argmin over the 128 codes this wave owns
    #pragma unroll
    for(int mt=0;mt<4;mt++){
        float bv[4]; int bix[4];
        #pragma unroll
        for(int r=0;r<4;r++){ bv[r] = 3.4e38f; bix[r] = 0; }
        #pragma unroll
        for(int nt=0;nt<8;nt++){
            int e = e0 + wc*128 + nt*16 + m;
            float cn = cnorm[e];
            #pragma unroll
            for(int r=0;r<4;r++){
                float vv = cn - 2.0f*acc[mt][nt][r];
                if(vv < bv[r]){ bv[r] = vv; bix[r] = e; }
            }
        }
        #pragma unroll
        for(int r=0;r<4;r++){
            float vv = bv[r]; int ix = bix[r];
            #pragma unroll
            for(int mk=8;mk;mk>>=1){
                float ov = __shfl_xor(vv, mk, 64);
                int   oi = __shfl_xor(ix, mk, 64);
                if(ov < vv || (ov == vv && oi < ix)){ vv = ov; ix = oi; }
            }
            if(m == 0){
                int n = n_base + wr*64 + mt*16 + quad*4 + r;
                int slot = blockIdx.y*2 + wc;
                pmin[n*4 + slot] = vv;
                pidx[n*4 + slot] = ix;
            }
        }
    }
}

// ---------------- finalize: one block per batch b; LDS histogram ----------------
__global__ __launch_bounds__(1024) void k_fin(const float* __restrict__ pmin, const int* __restrict__ pidx,
                                              int* __restrict__ idx,
                                              int* __restrict__ counts, int* __restrict__ countb,
                                              double* __restrict__ loss_sum){
    int b = blockIdx.x;
    int t = threadIdx.x;
    __shared__ int hist[NE];
    __shared__ float red[16];
    #pragma unroll
    for(int e=t; e<NE; e+=1024) hist[e] = 0;
    __syncthreads();
    float msum = 0.f;
    int n0 = b * (NCq*NCq);
    for(int i=t; i<NCq*NCq; i+=1024){
        int n = n0 + i;
        float4 pv = *(const float4*)&pmin[n*4];
        int4   pi = *(const int4*)&pidx[n*4];
        float bv = pv.x; int bix = pi.x;
        if(pv.y < bv || (pv.y==bv && pi.y<bix)){ bv=pv.y; bix=pi.y; }
        if(pv.z < bv || (pv.z==bv && pi.z<bix)){ bv=pv.z; bix=pi.z; }
        if(pv.w < bv || (pv.w==bv && pi.w<bix)){ bv=pv.w; bix=pi.w; }
        idx[n] = bix;
        atomicAdd(&hist[bix], 1);
        msum += bv;
    }
    #pragma unroll
    for(int m=32;m;m>>=1) msum += __shfl_xor(msum, m, 64);
    if((t&63)==0) red[t>>6] = msum;
    __syncthreads();
    if(t==0){
        float s = 0.f;
        #pragma unroll
        for(int i2=0;i2<16;i2++) s += red[i2];
        atomicAdd(loss_sum, (double)s);
    }
    for(int e=t; e<NE; e+=1024){
        int c = hist[e];
        countb[b*NE + e] = c;
        if(c) atomicAdd(&counts[e], c);
    }
}

// ---------------- scalars: vq_loss and usage ----------------
__global__ __launch_bounds__(256) void k_scal(const int* __restrict__ counts, const double* __restrict__ loss_sum,
                                              float* __restrict__ out){
    int t = threadIdx.x;
    float ent = 0.f;
    for(int e=t; e<NE; e+=256){
        float pr = (float)counts[e] / (float)NZ;
        ent += pr * logf(pr + 1e-10f);
    }
    #pragma unroll
    for(int m=32;m;m>>=1) ent += __shfl_xor(ent,m,64);
    __shared__ float red[4];
    if((t&63)==0) red[t>>6]=ent;
    __syncthreads();
    if(t==0){
        float e2 = red[0]+red[1]+red[2]+red[3];
        out[1+NZ] = expf(-e2);
        out[0] = (float)(1.25 * (*loss_sum) / ((double)NZ * (double)F_));
    }
}

// ---------------- SE block ----------------
__global__ __launch_bounds__(256) void k_se(const int* __restrict__ countb, const float* __restrict__ cb,
                                            const float* __restrict__ w1, const float* __restrict__ b1,
                                            const float* __restrict__ w2, const float* __restrict__ b2,
                                            float* __restrict__ s2p1){
    int b = blockIdx.x; int d = threadIdx.x;
    __shared__ float cnt[NE];
    __shared__ float s_sh[F_];
    __shared__ float h_sh[16];
    cnt[d]       = (float)countb[b*NE + d];
    cnt[d + 256] = (float)countb[b*NE + d + 256];
    __syncthreads();
    float s = 0.f;
    for(int e=0;e<NE;e++) s = fmaf(cnt[e], cb[e*F_ + d], s);
    s *= (1.0f/(float)(NCq*NCq));
    s_sh[d] = s;
    __syncthreads();
    if(d < 16){
        float h = b1[d];
        for(int k=0;k<F_;k++) h = fmaf(s_sh[k], w1[k*16 + d], h);
        h_sh[d] = fmaxf(h, 0.f);
    }
    __syncthreads();
    float v = b2[d];
    #pragma unroll
    for(int r=0;r<16;r++) v = fmaf(h_sh[r], w2[r*F_ + d], v);
    s2p1[b*F_ + d] = 1.0f + 1.0f/(1.0f + expf(-v));
}

// ---------------- w[b,e] = sum_d elu(c[e,d]*(1+s2[b,d])) ----------------
__global__ __launch_bounds__(256) void k_w(const float* __restrict__ cb, const float* __restrict__ s2p1,
                                           float* __restrict__ wtab){
    int b = blockIdx.x; int eg = blockIdx.y;
    int wv = threadIdx.x>>6, lane = threadIdx.x&63;
    __shared__ float m_sh[F_];
    m_sh[threadIdx.x] = s2p1[b*F_ + threadIdx.x];
    __syncthreads();
    int e = eg*4 + wv;
    float4 c4 = *(const float4*)&cb[e*F_ + lane*4];
    float s = eluf(c4.x*m_sh[lane*4]) + eluf(c4.y*m_sh[lane*4+1])
            + eluf(c4.z*m_sh[lane*4+2]) + eluf(c4.w*m_sh[lane*4+3]);
    #pragma unroll
    for(int m2=32;m2;m2>>=1) s += __shfl_xor(s,m2,64);
    if(lane==0) wtab[b*NE + e] = s;
}

// ---------------- final: out[b,i,j] = normalize_j(elu(w[b, idx])) ----------------
__global__ __launch_bounds__(64) void k_out(const int* __restrict__ idx, const float* __restrict__ wtab,
                                            float* __restrict__ out){
    int bi = blockIdx.x; int j = threadIdx.x;
    int b = bi / NCq;
    float v = 0.f;
    if(j < NCq) v = eluf(wtab[b*NE + idx[bi*NCq + j]]);
    float a = fabsf(v);
    #pragma unroll
    for(int m=32;m;m>>=1) a += __shfl_xor(a,m,64);
    if(j < NCq) out[1 + bi*NCq + j] = v / (a + EPSF);
}

extern "C" void kernel_launch(void* const* d_in, const int* in_sizes, int n_in,
                              void* d_out, int out_size, void* d_ws, size_t ws_size,
                              hipStream_t stream){
    (void)in_sizes; (void)n_in; (void)out_size; (void)ws_size;
    const float* x    = (const float*)d_in[0];
    const float* p    = (const float*)d_in[1];
    const float* bias = (const float*)d_in[2];
    const float* q    = (const float*)d_in[3];
    const float* th   = (const float*)d_in[4];
    const float* cb   = (const float*)d_in[5];
    const float* w1   = (const float*)d_in[6];
    const float* b1   = (const float*)d_in[7];
    const float* w2   = (const float*)d_in[8];
    const float* b2   = (const float*)d_in[9];
    float* out = (float*)d_out;
    char* ws = (char*)d_ws;
    size_t off = 0;
    auto alloc = [&](size_t bytes){ void* ptr = ws + off; off = (off + bytes + 255) & ~255ull; return ptr; };
    _Float16* Gf   = (_Float16*)alloc((size_t)NZ*F_*sizeof(_Float16));      // 60 MiB (doubles as Zf)
    _Float16* THf  = (_Float16*)alloc((size_t)F_*NCOL*sizeof(_Float16));    // 7.75 MiB ([n][k])
    _Float16* Tf   = (_Float16*)alloc((size_t)M_*F_*sizeof(_Float16));
    _Float16* CBf  = (_Float16*)alloc((size_t)NE*F_*sizeof(_Float16));
    float*    CN   = (float*)   alloc((size_t)NE*sizeof(float));
    float*    PMIN = (float*)   alloc((size_t)NZ*4*sizeof(float));
    int*      PIDX = (int*)     alloc((size_t)NZ*4*sizeof(int));
    int*      IDX  = (int*)     alloc((size_t)NZ*sizeof(int));
    char*     zbase= (char*)    alloc(8 + NE*sizeof(int));
    double*   LOSS   = (double*)zbase;
    int*      COUNTS = (int*)(zbase + 8);
    int*      COUNTB = (int*)   alloc((size_t)B_*NE*sizeof(int));
    float*    S2P1 = (float*)alloc((size_t)B_*F_*sizeof(float));
    float*    WTAB = (float*)alloc((size_t)B_*NE*sizeof(float));

    (void)hipMemsetAsync(zbase, 0, 8 + NE*sizeof(int), stream);
    dim3 gth(NCOL/32, F_/32);
    k_split_th<<<gth, 256, 0, stream>>>(th, THf);
    k_prep<<<NE, 256, 0, stream>>>(cb, CBf, CN, out + 1 + NZ + 1);
    k_ot<<<M_, 256, 0, stream>>>(x, p, bias, q, Tf);
    dim3 g3((M_ + 127)/128, NCOL/256);   // 16 x 62 (tail rows guarded)
    k_gemm_g<<<g3, 256, 0, stream>>>(Tf, THf, Gf);
    k_den<<<M_, 256, 0, stream>>>(Gf, LOSS);
    dim3 g5(NZ/128, 2);
    k_vq<<<g5, 256, 0, stream>>>(Gf, CBf, CN, PMIN, PIDX);
    k_fin<<<B_, 1024, 0, stream>>>(PMIN, PIDX, IDX, COUNTS, COUNTB, LOSS);
    k_scal<<<1, 256, 0, stream>>>(COUNTS, LOSS, out);
    k_se<<<B_, 256, 0, stream>>>(COUNTB, cb, w1, b1, w2, b2, S2P1);
    dim3 g8(B_, NE/4);
    k_w<<<g8, 256, 0, stream>>>(cb, S2P1, WTAB);
    k_out<<<M_, 64, 0, stream>>>(IDX, WTAB, out);
}

// Round 12
// 299.043 us; speedup vs baseline: 1.1687x; 1.0101x over previous
//
#include <hip/hip_runtime.h>
#include <math.h>

#define B_   32
#define NCq  62
#define F_   256
#define NE   512
#define M_   (B_*NCq)      // 1984
#define NCOL (NCq*F_)      // 15872
#define NZ   (M_*NCq)      // 123008
#define EPSF 1e-6f

typedef _Float16 h8_t __attribute__((ext_vector_type(8)));
typedef float f4_t __attribute__((ext_vector_type(4)));

__device__ __forceinline__ float eluf(float x){ return x > 0.0f ? x : expm1f(x); }

// XOR-swizzled LDS offset for BK=64: row stride 64 f16 (128B), 8 pieces of 8 f16 (16B)
__device__ __forceinline__ int sw64(int row, int piece){
    return row*64 + ((piece ^ (row&7))*8);
}
// async global->LDS, 16B per lane; lds base wave-uniform, lane i lands at base+i*16
__device__ __forceinline__ void gl_lds(const _Float16* g, _Float16* l){
    __builtin_amdgcn_global_load_lds((const __attribute__((address_space(1))) void*)g,
                                     (__attribute__((address_space(3))) void*)l, 16, 0, 0);
}

// ---------------- fused prep: theta transpose+f16 | codebook prep | o,t ----------------
#define NB_SPLIT (496*8)
#define NB_PREP  NE
#define NB_OT    M_
__global__ __launch_bounds__(256) void k_pre(const float* __restrict__ TH, _Float16* __restrict__ THf,
                                             const float* __restrict__ cb, _Float16* __restrict__ CBf,
                                             float* __restrict__ cnorm, float* __restrict__ out_cb,
                                             const float* __restrict__ x, const float* __restrict__ p,
                                             const float* __restrict__ bias, const float* __restrict__ q,
                                             _Float16* __restrict__ Tf){
    int bid = blockIdx.x;
    int tid = threadIdx.x;
    if(bid < NB_SPLIT){
        // theta: THf[n][k] = f16(TH[k][n])
        __shared__ float tile[32][33];
        int n0 = (bid % 496) * 32, k0 = (bid / 496) * 32;
        int cc = tid & 31, rr = tid >> 5;
        #pragma unroll
        for(int pp=0;pp<4;pp++){
            int kk = rr + pp*8;
            tile[kk][cc] = TH[(size_t)(k0+kk)*NCOL + n0 + cc];
        }
        __syncthreads();
        #pragma unroll
        for(int pp=0;pp<4;pp++){
            int nn = rr + pp*8;
            THf[(size_t)(n0+nn)*F_ + k0 + cc] = (_Float16)tile[cc][nn];
        }
    } else if(bid < NB_SPLIT + NB_PREP){
        // codebook: f16 copy, norms, output copy
        int e = bid - NB_SPLIT; int d = tid;
        float v = cb[e*F_ + d];
        out_cb[e*F_ + d] = v;
        CBf[e*F_ + d] = (_Float16)v;
        float s = v*v;
        #pragma unroll
        for(int m=32;m;m>>=1) s += __shfl_xor(s, m, 64);
        __shared__ float red[4];
        if((tid & 63)==0) red[tid>>6] = s;
        __syncthreads();
        if(tid==0) cnorm[e] = red[0]+red[1]+red[2]+red[3];
    } else {
        // o = p@x+bias; t = o@q; f16 t
        int bi = bid - NB_SPLIT - NB_PREP; int d = tid;
        int b = bi / NCq, i = bi % NCq;
        __shared__ float pr[NCq];
        __shared__ float orow[F_];
        if(d < NCq) pr[d] = p[i*NCq + d];
        __syncthreads();
        float acc = bias[i*F_ + d];
        const float* xb = x + (size_t)b*NCq*F_ + d;
        #pragma unroll 2
        for(int j=0;j<NCq;j++) acc = fmaf(pr[j], xb[j*F_], acc);
        orow[d] = acc;
        __syncthreads();
        float t = 0.f;
        #pragma unroll 4
        for(int k=0;k<F_;k++) t = fmaf(orow[k], q[k*F_ + d], t);
        Tf[bi*F_ + d] = (_Float16)t;
    }
}

// ---------------- G = ELU(T @ theta), f16 in/out, BK=64 (R9-best config) ----------------
__global__ __launch_bounds__(256,2) void k_gemm_g(const _Float16* __restrict__ Tf,
                                                  const _Float16* __restrict__ THf,
                                                  _Float16* __restrict__ Gf){
    __shared__ _Float16 As[128*64], Bs[256*64];  // 48 KB
    int tid = threadIdx.x;
    int l = tid & 63, w = tid >> 6;
    int wr = w >> 1, wc = w & 1;
    int m = l & 15, quad = l >> 4;
    int row0 = blockIdx.x * 128, col0 = blockIdx.y * 256;
    int wbase = tid & 192;
    f4_t acc[4][8] = {};
    for(int kc=0; kc<F_; kc+=64){
        #pragma unroll
        for(int p2=0;p2<4;p2++){
            int idx = p2*256 + tid;
            int row = idx >> 3, psw = idx & 7;
            int porig = psw ^ (row&7);
            int rclamp = row0 + row; if(rclamp >= M_) rclamp = M_-1;
            gl_lds(&Tf[(size_t)rclamp*F_ + kc + porig*8], &As[(p2*256 + wbase)*8]);
        }
        #pragma unroll
        for(int p2=0;p2<8;p2++){
            int idx = p2*256 + tid;
            int row = idx >> 3, psw = idx & 7;
            int porig = psw ^ (row&7);
            gl_lds(&THf[(size_t)(col0 + row)*F_ + kc + porig*8], &Bs[(p2*256 + wbase)*8]);
        }
        __syncthreads();
        #pragma unroll
        for(int ks=0;ks<2;ks++){
            h8_t a[4];
            #pragma unroll
            for(int mt=0;mt<4;mt++){
                int row = wr*64 + mt*16 + m;
                a[mt] = *(const h8_t*)&As[sw64(row, ks*4 + quad)];
            }
            #pragma unroll
            for(int nt=0;nt<8;nt++){
                int col = wc*128 + nt*16 + m;
                h8_t b = *(const h8_t*)&Bs[sw64(col, ks*4 + quad)];
                #pragma unroll
                for(int mt=0;mt<4;mt++)
                    acc[mt][nt] = __builtin_amdgcn_mfma_f32_16x16x32_f16(a[mt], b, acc[mt][nt], 0,0,0);
            }
        }
        __syncthreads();
    }
    #pragma unroll
    for(int mt=0;mt<4;mt++){
        #pragma unroll
        for(int nt=0;nt<8;nt++){
            int rowb = row0 + wr*64 + mt*16 + quad*4;
            int colb = col0 + wc*128 + nt*16 + m;
            #pragma unroll
            for(int r=0;r<4;r++){
                int row = rowb + r;
                if(row < M_) Gf[(size_t)row*NCOL + colb] = (_Float16)eluf(acc[mt][nt][r]);
            }
        }
    }
}

// ---------------- den + loss partial; renormalize Gf IN PLACE to f16 z ----------------
__global__ __launch_bounds__(256) void k_den(_Float16* __restrict__ Gf, float* __restrict__ lp){
    int bi = blockIdx.x;
    int tid = threadIdx.x;
    int dg = tid & 31, jg = tid >> 5;
    __shared__ float l1[8][32][8];
    __shared__ float l2[8][32][8];
    __shared__ float invsh[32][8];
    float v[8][8];
    float a1[8] = {}, a2[8] = {};
    size_t base = (size_t)bi*NCOL + dg*8;
    #pragma unroll
    for(int p=0;p<8;p++){
        int j = jg + p*8;
        if(j < NCq){
            h8_t g = *(const h8_t*)&Gf[base + (size_t)j*F_];
            #pragma unroll
            for(int i=0;i<8;i++){
                float t = (float)g[i];
                v[p][i] = t;
                a1[i] += fabsf(t);
                a2[i] = fmaf(t, t, a2[i]);
            }
        }
    }
    #pragma unroll
    for(int i=0;i<8;i++){ l1[jg][dg][i] = a1[i]; l2[jg][dg][i] = a2[i]; }
    __syncthreads();
    if(jg == 0){
        float part = 0.f;
        #pragma unroll
        for(int i=0;i<8;i++){
            float s1 = 0.f, s2 = 0.f;
            #pragma unroll
            for(int q2=0;q2<8;q2++){ s1 += l1[q2][dg][i]; s2 += l2[q2][dg][i]; }
            float inv = 1.0f/(s1 + EPSF);
            invsh[dg][i] = inv;
            part += s2*inv*inv;
        }
        #pragma unroll
        for(int mk=16;mk;mk>>=1) part += __shfl_xor(part, mk, 32);
        if(tid == 0) lp[bi] = part;
    }
    __syncthreads();
    float inv[8];
    #pragma unroll
    for(int i=0;i<8;i++) inv[i] = invsh[dg][i];
    #pragma unroll
    for(int p=0;p<8;p++){
        int j = jg + p*8;
        if(j < NCq){
            h8_t z;
            #pragma unroll
            for(int i=0;i<8;i++) z[i] = (_Float16)(v[p][i]*inv[i]);
            *(h8_t*)&Gf[base + (size_t)j*F_] = z;
        }
    }
}

// ---------------- VQ: dist GEMM (f16 MFMA, BK=64, single buffer) + argmin ----------------
__global__ __launch_bounds__(256,2) void k_vq(const _Float16* __restrict__ Zf,
                                              const _Float16* __restrict__ CBf,
                                              const float* __restrict__ cnorm,
                                              float* __restrict__ pmin, int* __restrict__ pidx){
    __shared__ _Float16 As[128*64], Bs[256*64];   // 48 KB
    int tid = threadIdx.x;
    int l = tid & 63, w = tid >> 6;
    int wr = w >> 1, wc = w & 1;
    int m = l & 15, quad = l >> 4;
    int n_base = blockIdx.x * 128;
    int e0 = blockIdx.y * 256;
    int wbase = tid & 192;
    f4_t acc[4][8] = {};
    for(int kc=0; kc<F_; kc+=64){
        #pragma unroll
        for(int p2=0;p2<4;p2++){
            int idx = p2*256 + tid;
            int row = idx >> 3, psw = idx & 7;
            int porig = psw ^ (row&7);
            gl_lds(&Zf[(size_t)(n_base + row)*F_ + kc + porig*8], &As[(p2*256 + wbase)*8]);
        }
        #pragma unroll
        for(int p2=0;p2<8;p2++){
            int idx = p2*256 + tid;
            int row = idx >> 3, psw = idx & 7;
            int porig = psw ^ (row&7);
            gl_lds(&CBf[(size_t)(e0 + row)*F_ + kc + porig*8], &Bs[(p2*256 + wbase)*8]);
        }
        __syncthreads();
        #pragma unroll
        for(int ks=0;ks<2;ks++){
            h8_t a[4];
            #pragma unroll
            for(int mt=0;mt<4;mt++){
                int row = wr*64 + mt*16 + m;
                a[mt] = *(const h8_t*)&As[sw64(row, ks*4 + quad)];
            }
            #pragma unroll
            for(int nt=0;nt<8;nt++){
                int col = wc*128 + nt*16 + m;
                h8_t b = *(const h8_t*)&Bs[sw64(col, ks*4 + quad)];
                #pragma unroll
                for(int mt=0;mt<4;mt++)
                    acc[mt][nt] = __builtin_amdgcn_mfma_f32_16x16x32_f16(a[mt], b, acc[mt][nt], 0,0,0);
            }
        }
        __syncthreads();
    }
    #pragma unroll
    for(int mt=0;mt<4;mt++){
        float bv[4]; int bix[4];
        #pragma unroll
        for(int r=0;r<4;r++){ bv[r] = 3.4e38f; bix[r] = 0; }
        #pragma unroll
        for(int nt=0;nt<8;nt++){
            int e = e0 + wc*128 + nt*16 + m;
            float cn = cnorm[e];
            #pragma unroll
            for(int r=0;r<4;r++){
                float vv = cn - 2.0f*acc[mt][nt][r];
                if(vv < bv[r]){ bv[r] = vv; bix[r] = e; }
            }
        }
        #pragma unroll
        for(int r=0;r<4;r++){
            float vv = bv[r]; int ix = bix[r];
            #pragma unroll
            for(int mk=8;mk;mk>>=1){
                float ov = __shfl_xor(vv, mk, 64);
                int   oi = __shfl_xor(ix, mk, 64);
                if(ov < vv || (ov == vv && oi < ix)){ vv = ov; ix = oi; }
            }
            if(m == 0){
                int n = n_base + wr*64 + mt*16 + quad*4 + r;
                int slot = blockIdx.y*2 + wc;
                pmin[n*4 + slot] = vv;
                pidx[n*4 + slot] = ix;
            }
        }
    }
}

// ---------------- fused post: argmin finalize + hist + SE + wtab + output ----------------
__global__ __launch_bounds__(1024) void k_post(const float* __restrict__ pmin, const int* __restrict__ pidx,
                                               int* __restrict__ idx, int* __restrict__ countb,
                                               float* __restrict__ lossb,
                                               const float* __restrict__ cb,
                                               const float* __restrict__ w1, const float* __restrict__ b1,
                                               const float* __restrict__ w2, const float* __restrict__ b2,
                                               float* __restrict__ out){
    int b = blockIdx.x;
    int t = threadIdx.x;
    __shared__ int hist[NE];
    __shared__ float red[16];
    __shared__ float sp[4][F_];
    __shared__ float s_sh[F_];
    __shared__ float h_sh[16];
    __shared__ float s2p1[F_];
    __shared__ float wt[NE];
    for(int e=t; e<NE; e+=1024) hist[e] = 0;
    __syncthreads();
    // phase 1: argmin finalize + LDS hist + loss partial
    float msum = 0.f;
    int n0 = b * (NCq*NCq);
    for(int i=t; i<NCq*NCq; i+=1024){
        int n = n0 + i;
        float4 pv = *(const float4*)&pmin[n*4];
        int4   pi = *(const int4*)&pidx[n*4];
        float bv = pv.x; int bix = pi.x;
        if(pv.y < bv || (pv.y==bv && pi.y<bix)){ bv=pv.y; bix=pi.y; }
        if(pv.z < bv || (pv.z==bv && pi.z<bix)){ bv=pv.z; bix=pi.z; }
        if(pv.w < bv || (pv.w==bv && pi.w<bix)){ bv=pv.w; bix=pi.w; }
        idx[n] = bix;
        atomicAdd(&hist[bix], 1);
        msum += bv;
    }
    #pragma unroll
    for(int m=32;m;m>>=1) msum += __shfl_xor(msum, m, 64);
    if((t&63)==0) red[t>>6] = msum;
    __syncthreads();   // hist + red complete
    if(t==0){
        float s = 0.f;
        #pragma unroll
        for(int i2=0;i2<16;i2++) s += red[i2];
        lossb[b] = s;
    }
    for(int e=t; e<NE; e+=1024) countb[b*NE + e] = hist[e];
    // phase 2: SE squeeze + MLP
    {
        int d = t & 255, qq = t >> 8;   // qq in 0..3
        float s = 0.f;
        for(int e=qq*128; e<(qq+1)*128; e++) s = fmaf((float)hist[e], cb[e*F_ + d], s);
        sp[qq][d] = s;
    }
    __syncthreads();
    if(t < F_) s_sh[t] = (sp[0][t]+sp[1][t]+sp[2][t]+sp[3][t]) * (1.0f/(float)(NCq*NCq));
    __syncthreads();
    if(t < 16){
        float h = b1[t];
        for(int k=0;k<F_;k++) h = fmaf(s_sh[k], w1[k*16 + t], h);
        h_sh[t] = fmaxf(h, 0.f);
    }
    __syncthreads();
    if(t < F_){
        float v = b2[t];
        #pragma unroll
        for(int r=0;r<16;r++) v = fmaf(h_sh[r], w2[r*F_ + t], v);
        s2p1[t] = 1.0f + 1.0f/(1.0f + expf(-v));
    }
    __syncthreads();
    // phase 3: wt[e] = sum_d elu(cb[e,d]*s2p1[d])
    {
        int wv = t >> 6, lane = t & 63;
        for(int e = wv; e < NE; e += 16){
            float4 c4 = *(const float4*)&cb[e*F_ + lane*4];
            float s = eluf(c4.x*s2p1[lane*4]) + eluf(c4.y*s2p1[lane*4+1])
                    + eluf(c4.z*s2p1[lane*4+2]) + eluf(c4.w*s2p1[lane*4+3]);
            #pragma unroll
            for(int m2=32;m2;m2>>=1) s += __shfl_xor(s, m2, 64);
            if(lane==0) wt[e] = s;
        }
    }
    __syncthreads();
    // phase 4: output rows
    {
        int wv = t >> 6, lane = t & 63;
        for(int i = wv; i < NCq; i += 16){
            int bi = b*NCq + i;
            float v = 0.f;
            if(lane < NCq) v = eluf(wt[idx[bi*NCq + lane]]);
            float a = fabsf(v);
            #pragma unroll
            for(int m2=32;m2;m2>>=1) a += __shfl_xor(a, m2, 64);
            if(lane < NCq) out[1 + bi*NCq + lane] = v / (a + EPSF);
        }
    }
}

// ---------------- scalars: vq_loss and usage (from partials) ----------------
__global__ __launch_bounds__(256) void k_scal(const int* __restrict__ countb,
                                              const float* __restrict__ lp, const float* __restrict__ lossb,
                                              float* __restrict__ out){
    int t = threadIdx.x;
    float ent = 0.f;
    for(int e=t; e<NE; e+=256){
        int c = 0;
        #pragma unroll 4
        for(int b=0;b<B_;b++) c += countb[b*NE + e];
        float pr = (float)c / (float)NZ;
        ent += pr * logf(pr + 1e-10f);
    }
    float ls = 0.f;
    for(int i=t; i<M_; i+=256) ls += lp[i];
    if(t < B_) ls += lossb[t];
    #pragma unroll
    for(int m=32;m;m>>=1){ ent += __shfl_xor(ent,m,64); ls += __shfl_xor(ls,m,64); }
    __shared__ float red[4], red2[4];
    if((t&63)==0){ red[t>>6]=ent; red2[t>>6]=ls; }
    __syncthreads();
    if(t==0){
        float e2 = red[0]+red[1]+red[2]+red[3];
        float l2 = red2[0]+red2[1]+red2[2]+red2[3];
        out[1+NZ] = expf(-e2);
        out[0] = (float)(1.25 * (double)l2 / ((double)NZ * (double)F_));
    }
}

extern "C" void kernel_launch(void* const* d_in, const int* in_sizes, int n_in,
                              void* d_out, int out_size, void* d_ws, size_t ws_size,
                              hipStream_t stream){
    (void)in_sizes; (void)n_in; (void)out_size; (void)ws_size;
    const float* x    = (const float*)d_in[0];
    const float* p    = (const float*)d_in[1];
    const float* bias = (const float*)d_in[2];
    const float* q    = (const float*)d_in[3];
    const float* th   = (const float*)d_in[4];
    const float* cb   = (const float*)d_in[5];
    const float* w1   = (const float*)d_in[6];
    const float* b1   = (const float*)d_in[7];
    const float* w2   = (const float*)d_in[8];
    const float* b2   = (const float*)d_in[9];
    float* out = (float*)d_out;
    char* ws = (char*)d_ws;
    size_t off = 0;
    auto alloc = [&](size_t bytes){ void* ptr = ws + off; off = (off + bytes + 255) & ~255ull; return ptr; };
    _Float16* Gf   = (_Float16*)alloc((size_t)NZ*F_*sizeof(_Float16));      // 60 MiB (doubles as Zf)
    _Float16* THf  = (_Float16*)alloc((size_t)F_*NCOL*sizeof(_Float16));    // 7.75 MiB ([n][k])
    _Float16* Tf   = (_Float16*)alloc((size_t)M_*F_*sizeof(_Float16));
    _Float16* CBf  = (_Float16*)alloc((size_t)NE*F_*sizeof(_Float16));
    float*    CN   = (float*)   alloc((size_t)NE*sizeof(float));
    float*    PMIN = (float*)   alloc((size_t)NZ*4*sizeof(float));
    int*      PIDX = (int*)     alloc((size_t)NZ*4*sizeof(int));
    int*      IDX  = (int*)     alloc((size_t)NZ*sizeof(int));
    float*    LP    = (float*)  alloc((size_t)M_*sizeof(float));
    float*    LOSSB = (float*)  alloc((size_t)B_*sizeof(float));
    int*      COUNTB= (int*)    alloc((size_t)B_*NE*sizeof(int));

    k_pre<<<NB_SPLIT + NB_PREP + NB_OT, 256, 0, stream>>>(th, THf, cb, CBf, CN, out + 1 + NZ + 1,
                                                          x, p, bias, q, Tf);
    dim3 g3((M_ + 127)/128, NCOL/256);
    k_gemm_g<<<g3, 256, 0, stream>>>(Tf, THf, Gf);
    k_den<<<M_, 256, 0, stream>>>(Gf, LP);
    dim3 g5(NZ/128, 2);
    k_vq<<<g5, 256, 0, stream>>>(Gf, CBf, CN, PMIN, PIDX);
    k_post<<<B_, 1024, 0, stream>>>(PMIN, PIDX, IDX, COUNTB, LOSSB, cb, w1, b1, w2, b2, out);
    k_scal<<<1, 256, 0, stream>>>(COUNTB, LP, LOSSB, out);
}